// Round 9
// baseline (76.002 us; speedup 1.0000x reference)
//
#include <hip/hip_runtime.h>

// HEALPixPad: x (B=2, 12, C=32, 256, 256) f32 -> (B, 12, C, 260, 260) f32, P=2.
// Round 9: A/B experiment — identical to round 8 except bulk span stores are
// PLAIN stores instead of __builtin_nontemporal_store. Tests whether NT was
// (a) protecting L3 input residency (then this round regresses, FETCH rises)
// or (b) throttling the store path (then this round improves).

constexpr int N  = 256;
constexpr int P  = 2;
constexpr int NP = N + 2 * P;        // 260
constexpr int C  = 32;
constexpr int PLANE_OUT = NP * NP;   // 67600
constexpr int PLANE_IN  = N * N;     // 65536

typedef float f32x4 __attribute__((ext_vector_type(4)));

// Per-element gather with the full HEALPix neighbor mapping (round-1 verified).
__device__ __forceinline__ float gather(const float* __restrict__ in,
                                        int basePlane, int face, int i,
                                        int oh, int ow) {
    auto L = [&](int f, int sh, int sw) -> float {
        return in[(size_t)(basePlane + f * C) * PLANE_IN + sh * N + sw];
    };

    float v;
    if (face < 4) {
        // ---- northern polar cap ----
        if (oh < P) {
            if (ow < P)              v = L((i + 2) & 3, P - 1 - oh, P - 1 - ow);
            else if (ow < P + N)     v = L((i + 1) & 3, ow - P, P - 1 - oh);
            else                     v = L((i + 1) & 3, ow - P - N, P - 1 - oh);
        } else if (oh < P + N) {
            int ch = oh - P;
            if (ow < P)              v = L((i + 3) & 3, P - 1 - ow, ch);
            else if (ow < P + N)     v = L(face, ch, ow - P);
            else                     v = L(4 + ((i + 1) & 3), ch, ow - P - N);
        } else {
            int bh = oh - P - N;
            if (ow < P)              v = L((i + 3) & 3, bh, N - P + ow);
            else if (ow < P + N)     v = L(4 + i, bh, ow - P);
            else                     v = L(8 + i, bh, ow - P - N);
        }
    } else if (face < 8) {
        // ---- equatorial belt ----
        if (oh < P) {
            if (ow < P) {
                if (oh == P - 1 && ow == P - 1)
                    v = 0.5f * L(i, N - 1, 0) + 0.5f * L((i + 3) & 3, 0, N - 1);
                else if (oh == P - 1) v = L((i + 3) & 3, 0, N - P + ow);
                else if (ow == P - 1) v = L(i, N - P + oh, 0);
                else                  v = 0.0f;
            }
            else if (ow < P + N)     v = L(i, N - P + oh, ow - P);
            else                     v = L(i, N - P + oh, ow - P - N);
        } else if (oh < P + N) {
            int ch = oh - P;
            if (ow < P)              v = L((i + 3) & 3, ch, N - P + ow);
            else if (ow < P + N)     v = L(face, ch, ow - P);
            else                     v = L(4 + ((i + 1) & 3), ch, ow - P - N);
        } else {
            int bh = oh - P - N;
            if (ow < P)              v = L(4 + ((i + 3) & 3), bh, N - P + ow);
            else if (ow < P + N)     v = L(8 + i, bh, ow - P);
            else {
                int bw = ow - P - N;
                if (bh == 0 && bw == 0)
                    v = 0.5f * L(8 + i, 0, N - 1) + 0.5f * L(8 + ((i + 3) & 3), N - 1, 0);
                else if (bh == 0)     v = L(8 + ((i + 3) & 3), N - 1, bw);
                else if (bw == 0)     v = L(8 + i, bh, N - 1);
                else                  v = 0.0f;
            }
        }
    } else {
        // ---- southern polar cap ----
        if (oh < P) {
            if (ow < P)              v = L(4 + i, N - P + oh, ow);
            else if (ow < P + N)     v = L(4 + i, N - P + oh, ow - P);
            else                     v = L(i, N - P + oh, N - P + (ow - P - N));
        } else if (oh < P + N) {
            int ch = oh - P;
            if (ow < P)              v = L(4 + ((i + 1) & 3), ch, N - P + ow);
            else if (ow < P + N)     v = L(face, ch, ow - P);
            else {
                int bw = ow - P - N;
                v = L(8 + ((i + 1) & 3), N - 1 - bw, ch);
            }
        } else {
            int bh = oh - P - N;
            if (ow < P)              v = L(8 + ((i + 1) & 3), N - P + ow, N - 1 - bh);
            else if (ow < P + N)     v = L(8 + ((i + 3) & 3), ow - P, N - 1 - bh);
            else {
                int bw = ow - P - N;
                v = L(8 + ((i + 3) & 3), N - 1 - bh, N - 1 - bw);
            }
        }
    }
    return v;
}

__global__ __launch_bounds__(256)
void healpix_pad_kernel(const float* __restrict__ in, float* __restrict__ out) {
    __shared__ float edges[16][4];                     // [local row][l0,l1,r258,r259]
    __shared__ __align__(16) float rowbuf[2][NP];      // top or bottom gather rows

    const int plane = blockIdx.y;                  // (b*12 + face)*C + c
    const int bx    = blockIdx.x;                  // 0..16
    const int tid   = threadIdx.x;
    const int w     = tid >> 6;
    const int l     = tid & 63;
    const int s     = bx * 4 + w;                  // span id (4 output rows each)

    const int bc   = plane >> 5;                   // b*12 + face   (C=32)
    const int face = bc >= 12 ? bc - 12 : bc;
    const int fi   = face & 3;
    const int basePlane = plane - face * C;
    const float* __restrict__ iplane = in + (size_t)plane * PLANE_IN;
    float* __restrict__ oplane = out + (size_t)plane * PLANE_OUT;

    // ---- phase 0: issue all interior loads for my span (overlap with phase 1)
    const int r0 = s * 4;
    float2 A[5], B[5];
    if (s <= 64) {
        #pragma unroll
        for (int it = 0; it < 5; ++it) {
            int c = it * 64 + l; if (c > 259) c = 259;       // clamp dead lanes
            int q = c / 65, j = c - q * 65;
            int row = r0 + q;
            int ir  = row - P;                                // clamped input row
            ir = ir < 0 ? 0 : (ir > 255 ? 255 : ir);
            const float* src = iplane + ir * N;
            int off1 = (j == 0) ? 0 : (4 * j - 2);            // j==64 -> 254
            int off2 = (j >= 64) ? 252 : 4 * j;               // dummy for j==64
            A[it] = *reinterpret_cast<const float2*>(src + off1);
            B[it] = *reinterpret_cast<const float2*>(src + off2);
        }
    }

    // ---- phase 1: edge halo values into LDS (divergence confined here)
    if (tid < 64) {
        int row = bx * 16 + (tid >> 2);
        if (row >= P && row <= 257) {
            int e  = tid & 3;
            int ow = (e < 2) ? e : 256 + e;                   // 0,1,258,259
            edges[tid >> 2][e] = gather(in, basePlane, face, fi, row, ow);
        }
    }
    if (bx == 0 || bx == 16) {
        for (int t = tid; t < 2 * NP; t += 256) {
            int r01 = t >= NP ? 1 : 0;
            int col = t - NP * r01;
            int oh  = (bx == 0) ? r01 : 258 + r01;
            rowbuf[r01][col] = gather(in, basePlane, face, fi, oh, col);
        }
    }
    __syncthreads();

    if (s > 64) return;

    // ---- phase 2: branch-light assemble + 5 full-line span stores (PLAIN)
    #pragma unroll
    for (int it = 0; it < 5; ++it) {
        int c = it * 64 + l;
        if (c > 259) continue;                                // dead lanes (it==4)
        int q = c / 65, j = c - q * 65;
        int row = r0 + q;
        int ow  = 4 * j;

        f32x4 v;
        if (row < P || row > 257) {
            int rb = row < P ? row : row - 258;
            v = *reinterpret_cast<const f32x4*>(&rowbuf[rb][ow]);
        } else {
            int rl = row - bx * 16;
            float e0 = edges[rl][0], e1 = edges[rl][1];
            float e2 = edges[rl][2], e3 = edges[rl][3];
            float x  = (j == 0) ? e0 : A[it].x;
            float y  = (j == 0) ? e1 : A[it].y;
            float z  = (j == 0) ? A[it].x : ((j == 64) ? e2 : B[it].x);
            float wv = (j == 0) ? A[it].y : ((j == 64) ? e3 : B[it].y);
            v = f32x4{x, y, z, wv};
        }
        *reinterpret_cast<f32x4*>(oplane + row * NP + ow) = v;   // plain store
    }
}

extern "C" void kernel_launch(void* const* d_in, const int* in_sizes, int n_in,
                              void* d_out, int out_size, void* d_ws, size_t ws_size,
                              hipStream_t stream) {
    const float* in = (const float*)d_in[0];
    float* out = (float*)d_out;
    int planes = out_size / PLANE_OUT;             // 2*12*32 = 768
    dim3 block(256);
    dim3 grid(17, planes);                         // 17 blocks x 4 spans >= 65 spans
    healpix_pad_kernel<<<grid, block, 0, stream>>>(in, out);
}

// Round 10
// 70.453 us; speedup vs baseline: 1.0788x; 1.0788x over previous
//
#include <hip/hip_runtime.h>

// HEALPixPad: x (B=2, 12, C=32, 256, 256) f32 -> (B, 12, C, 260, 260) f32, P=2.
// FINAL (revert to round 8 after round-9 A/B: NT stores WIN, 70.7 vs 76.0 µs).
//   - Store unit: 4-output-row span = 4160 B = exactly 65 cache lines (aligned).
//     One wave per span, 5 wave-wide NT float4 stores -> zero write amplification
//     (WRITE_SIZE = 207 MB = ideal +0.2%).
//   - Phase 0: waves issue all interior float2 loads up front.
//   - Phase 1: 64 threads/block compute left/right edge halo values into LDS
//     (divergent gather confined, overlapped with phase-0 loads); blocks 0/16
//     additionally fill full top/bottom gather rows into LDS.
//   - Phase 2: branch-light selects, 5 back-to-back NT span stores.
// NT stores keep the 208 MB write stream from evicting the L3-resident input
// (round-9 A/B: plain stores -> +5.3 µs).

constexpr int N  = 256;
constexpr int P  = 2;
constexpr int NP = N + 2 * P;        // 260
constexpr int C  = 32;
constexpr int PLANE_OUT = NP * NP;   // 67600
constexpr int PLANE_IN  = N * N;     // 65536

typedef float f32x4 __attribute__((ext_vector_type(4)));

// Per-element gather with the full HEALPix neighbor mapping (round-1 verified).
__device__ __forceinline__ float gather(const float* __restrict__ in,
                                        int basePlane, int face, int i,
                                        int oh, int ow) {
    auto L = [&](int f, int sh, int sw) -> float {
        return in[(size_t)(basePlane + f * C) * PLANE_IN + sh * N + sw];
    };

    float v;
    if (face < 4) {
        // ---- northern polar cap ----
        if (oh < P) {
            if (ow < P)              v = L((i + 2) & 3, P - 1 - oh, P - 1 - ow);
            else if (ow < P + N)     v = L((i + 1) & 3, ow - P, P - 1 - oh);
            else                     v = L((i + 1) & 3, ow - P - N, P - 1 - oh);
        } else if (oh < P + N) {
            int ch = oh - P;
            if (ow < P)              v = L((i + 3) & 3, P - 1 - ow, ch);
            else if (ow < P + N)     v = L(face, ch, ow - P);
            else                     v = L(4 + ((i + 1) & 3), ch, ow - P - N);
        } else {
            int bh = oh - P - N;
            if (ow < P)              v = L((i + 3) & 3, bh, N - P + ow);
            else if (ow < P + N)     v = L(4 + i, bh, ow - P);
            else                     v = L(8 + i, bh, ow - P - N);
        }
    } else if (face < 8) {
        // ---- equatorial belt ----
        if (oh < P) {
            if (ow < P) {
                if (oh == P - 1 && ow == P - 1)
                    v = 0.5f * L(i, N - 1, 0) + 0.5f * L((i + 3) & 3, 0, N - 1);
                else if (oh == P - 1) v = L((i + 3) & 3, 0, N - P + ow);
                else if (ow == P - 1) v = L(i, N - P + oh, 0);
                else                  v = 0.0f;
            }
            else if (ow < P + N)     v = L(i, N - P + oh, ow - P);
            else                     v = L(i, N - P + oh, ow - P - N);
        } else if (oh < P + N) {
            int ch = oh - P;
            if (ow < P)              v = L((i + 3) & 3, ch, N - P + ow);
            else if (ow < P + N)     v = L(face, ch, ow - P);
            else                     v = L(4 + ((i + 1) & 3), ch, ow - P - N);
        } else {
            int bh = oh - P - N;
            if (ow < P)              v = L(4 + ((i + 3) & 3), bh, N - P + ow);
            else if (ow < P + N)     v = L(8 + i, bh, ow - P);
            else {
                int bw = ow - P - N;
                if (bh == 0 && bw == 0)
                    v = 0.5f * L(8 + i, 0, N - 1) + 0.5f * L(8 + ((i + 3) & 3), N - 1, 0);
                else if (bh == 0)     v = L(8 + ((i + 3) & 3), N - 1, bw);
                else if (bw == 0)     v = L(8 + i, bh, N - 1);
                else                  v = 0.0f;
            }
        }
    } else {
        // ---- southern polar cap ----
        if (oh < P) {
            if (ow < P)              v = L(4 + i, N - P + oh, ow);
            else if (ow < P + N)     v = L(4 + i, N - P + oh, ow - P);
            else                     v = L(i, N - P + oh, N - P + (ow - P - N));
        } else if (oh < P + N) {
            int ch = oh - P;
            if (ow < P)              v = L(4 + ((i + 1) & 3), ch, N - P + ow);
            else if (ow < P + N)     v = L(face, ch, ow - P);
            else {
                int bw = ow - P - N;
                v = L(8 + ((i + 1) & 3), N - 1 - bw, ch);
            }
        } else {
            int bh = oh - P - N;
            if (ow < P)              v = L(8 + ((i + 1) & 3), N - P + ow, N - 1 - bh);
            else if (ow < P + N)     v = L(8 + ((i + 3) & 3), ow - P, N - 1 - bh);
            else {
                int bw = ow - P - N;
                v = L(8 + ((i + 3) & 3), N - 1 - bh, N - 1 - bw);
            }
        }
    }
    return v;
}

__global__ __launch_bounds__(256)
void healpix_pad_kernel(const float* __restrict__ in, float* __restrict__ out) {
    __shared__ float edges[16][4];                     // [local row][l0,l1,r258,r259]
    __shared__ __align__(16) float rowbuf[2][NP];      // top or bottom gather rows

    const int plane = blockIdx.y;                  // (b*12 + face)*C + c
    const int bx    = blockIdx.x;                  // 0..16
    const int tid   = threadIdx.x;
    const int w     = tid >> 6;
    const int l     = tid & 63;
    const int s     = bx * 4 + w;                  // span id (4 output rows each)

    const int bc   = plane >> 5;                   // b*12 + face   (C=32)
    const int face = bc >= 12 ? bc - 12 : bc;
    const int fi   = face & 3;
    const int basePlane = plane - face * C;
    const float* __restrict__ iplane = in + (size_t)plane * PLANE_IN;
    float* __restrict__ oplane = out + (size_t)plane * PLANE_OUT;

    // ---- phase 0: issue all interior loads for my span (overlap with phase 1)
    const int r0 = s * 4;
    float2 A[5], B[5];
    if (s <= 64) {
        #pragma unroll
        for (int it = 0; it < 5; ++it) {
            int c = it * 64 + l; if (c > 259) c = 259;       // clamp dead lanes
            int q = c / 65, j = c - q * 65;
            int row = r0 + q;
            int ir  = row - P;                                // clamped input row
            ir = ir < 0 ? 0 : (ir > 255 ? 255 : ir);
            const float* src = iplane + ir * N;
            int off1 = (j == 0) ? 0 : (4 * j - 2);            // j==64 -> 254
            int off2 = (j >= 64) ? 252 : 4 * j;               // dummy for j==64
            A[it] = *reinterpret_cast<const float2*>(src + off1);
            B[it] = *reinterpret_cast<const float2*>(src + off2);
        }
    }

    // ---- phase 1: edge halo values into LDS (divergence confined here)
    if (tid < 64) {
        int row = bx * 16 + (tid >> 2);
        if (row >= P && row <= 257) {
            int e  = tid & 3;
            int ow = (e < 2) ? e : 256 + e;                   // 0,1,258,259
            edges[tid >> 2][e] = gather(in, basePlane, face, fi, row, ow);
        }
    }
    if (bx == 0 || bx == 16) {
        for (int t = tid; t < 2 * NP; t += 256) {
            int r01 = t >= NP ? 1 : 0;
            int col = t - NP * r01;
            int oh  = (bx == 0) ? r01 : 258 + r01;
            rowbuf[r01][col] = gather(in, basePlane, face, fi, oh, col);
        }
    }
    __syncthreads();

    if (s > 64) return;

    // ---- phase 2: branch-light assemble + 5 full-line NT span stores
    #pragma unroll
    for (int it = 0; it < 5; ++it) {
        int c = it * 64 + l;
        if (c > 259) continue;                                // dead lanes (it==4)
        int q = c / 65, j = c - q * 65;
        int row = r0 + q;
        int ow  = 4 * j;

        f32x4 v;
        if (row < P || row > 257) {
            int rb = row < P ? row : row - 258;
            v = *reinterpret_cast<const f32x4*>(&rowbuf[rb][ow]);
        } else {
            int rl = row - bx * 16;
            float e0 = edges[rl][0], e1 = edges[rl][1];
            float e2 = edges[rl][2], e3 = edges[rl][3];
            float x  = (j == 0) ? e0 : A[it].x;
            float y  = (j == 0) ? e1 : A[it].y;
            float z  = (j == 0) ? A[it].x : ((j == 64) ? e2 : B[it].x);
            float wv = (j == 0) ? A[it].y : ((j == 64) ? e3 : B[it].y);
            v = f32x4{x, y, z, wv};
        }
        __builtin_nontemporal_store(v, reinterpret_cast<f32x4*>(oplane + row * NP + ow));
    }
}

extern "C" void kernel_launch(void* const* d_in, const int* in_sizes, int n_in,
                              void* d_out, int out_size, void* d_ws, size_t ws_size,
                              hipStream_t stream) {
    const float* in = (const float*)d_in[0];
    float* out = (float*)d_out;
    int planes = out_size / PLANE_OUT;             // 2*12*32 = 768
    dim3 block(256);
    dim3 grid(17, planes);                         // 17 blocks x 4 spans >= 65 spans
    healpix_pad_kernel<<<grid, block, 0, stream>>>(in, out);
}